// Round 3
// baseline (163.891 us; speedup 1.0000x reference)
//
#include <hip/hip_runtime.h>
#include <math.h>

// Problem constants: B=1048576, DX=32, DS=16, H=128, K=64, NSN=4
#define DXc 32
#define DSc 16
#define Hc  128
#define Kc  64
#define NSNc 4

// LDS staging buffer, reused across phases.
// x stage:      256 rows x 9 float4 (8 used, +1 pad)  = 36864 B
// hidden chunk:  64 rows x 33 float4 (32 used, +1 pad) = 33792 B
// s stage:      256 rows x 5 float4 (4 used, +1 pad)   = 20480 B
union SMemU {
    float4 sx[256 * 9];
    float4 shid[64 * 33];
    float4 ss[256 * 5];
};

__global__ __launch_bounds__(256, 3) void snclust_fused(
    const float* __restrict__ x,
    const float* __restrict__ s,
    const float* __restrict__ hidden,
    const float* __restrict__ naive_pred,
    const float* __restrict__ centers,
    const float* __restrict__ W_tune,
    const float* __restrict__ b_tune,
    const float* __restrict__ W_sn,
    const float* __restrict__ b_sn,
    const float* __restrict__ rsw,
    float* __restrict__ out,
    int n)
{
    __shared__ SMemU sm;
    __shared__ float sWc[Kc][DSc + 1];
    __shared__ float sbc[Kc];
    __shared__ float sc2[Kc];
    __shared__ float shdot[256];
    __shared__ float spart[64][5];

    const int tid = threadIdx.x;
    const size_t blockBase = (size_t)blockIdx.x * 256;

    // ---- Phase A: combined SN weights + center norms ----
    for (int e = tid; e < Kc * DSc; e += 256) {
        const int c = e >> 4;
        const int j = e & 15;
        float acc = 0.f;
#pragma unroll
        for (int nn = 0; nn < NSNc; ++nn)
            acc = fmaf(rsw[c * NSNc + nn], W_sn[(nn * Kc + c) * DSc + j], acc);
        sWc[c][j] = acc;
    }
    if (tid < Kc) {
        const int c = tid;
        float accb = 0.f;
#pragma unroll
        for (int nn = 0; nn < NSNc; ++nn)
            accb = fmaf(rsw[c * NSNc + nn], b_sn[nn * Kc + c], accb);
        sbc[c] = accb;
        float c2 = 0.f;
#pragma unroll
        for (int d = 0; d < DXc; ++d) {
            const float cv = centers[c * DXc + d];
            c2 = fmaf(cv, cv, c2);
        }
        sc2[c] = c2;
    }
    __syncthreads();

    if (blockBase + 256 <= (size_t)n) {
        // ================= FAST PATH: full block of 256 rows =================

        // ---- Phase B: stage x coalesced, copy own row to registers ----
        {
            const float4* gx = reinterpret_cast<const float4*>(x) + blockBase * 8;
#pragma unroll
            for (int i = 0; i < 8; ++i) {
                const int f = i * 256 + tid;               // [0,2048)
                sm.sx[(f >> 3) * 9 + (f & 7)] = gx[f];
            }
        }
        __syncthreads();
        float xr[DXc];
#pragma unroll
        for (int i = 0; i < 8; ++i) {
            const float4 v = sm.sx[tid * 9 + i];
            xr[i * 4 + 0] = v.x; xr[i * 4 + 1] = v.y;
            xr[i * 4 + 2] = v.z; xr[i * 4 + 3] = v.w;
        }
        __syncthreads();   // sx consumed; buffer free for hidden chunks

        // ---- Phase C: hidden . W_tune via 4 chunks of 64 rows ----
        {
            const float4* gh = reinterpret_cast<const float4*>(hidden) + blockBase * 32;
            const int r   = tid & 63;
            const int seg = __builtin_amdgcn_readfirstlane(tid >> 6); // wave-uniform
            for (int c = 0; c < 4; ++c) {
#pragma unroll
                for (int i = 0; i < 8; ++i) {
                    const int f = i * 256 + tid;           // [0,2048): row=f>>5, col4=f&31
                    sm.shid[(f >> 5) * 33 + (f & 31)] = gh[c * 2048 + f];
                }
                __syncthreads();
                float a0 = 0.f, a1 = 0.f;
                const int base = r * 33 + seg * 8;
#pragma unroll
                for (int j = 0; j < 4; ++j) {
                    const float4 v = sm.shid[base + 2 * j];
                    const float4 w = sm.shid[base + 2 * j + 1];
                    const int wb = seg * 32 + j * 8;
                    a0 = fmaf(v.x, W_tune[wb + 0], a0);
                    a0 = fmaf(v.y, W_tune[wb + 1], a0);
                    a0 = fmaf(v.z, W_tune[wb + 2], a0);
                    a0 = fmaf(v.w, W_tune[wb + 3], a0);
                    a1 = fmaf(w.x, W_tune[wb + 4], a1);
                    a1 = fmaf(w.y, W_tune[wb + 5], a1);
                    a1 = fmaf(w.z, W_tune[wb + 6], a1);
                    a1 = fmaf(w.w, W_tune[wb + 7], a1);
                }
                spart[r][seg] = a0 + a1;
                __syncthreads();
                if (tid < 64)
                    shdot[c * 64 + tid] =
                        (spart[tid][0] + spart[tid][1]) + (spart[tid][2] + spart[tid][3]);
            }
        }
        __syncthreads();
        const float hacc = shdot[tid];
        const float z = hacc + b_tune[0];
        const float x_tune = 1.0f / (1.0f + __expf(-z));

        // ---- Phase D: issue s-stage + naive loads, then dist/argmin (VALU) ----
        float4 st[4];
        {
            const float4* gs = reinterpret_cast<const float4*>(s) + blockBase * 4;
#pragma unroll
            for (int i = 0; i < 4; ++i)
                st[i] = gs[i * 256 + tid];                 // in flight during dist loop
        }
        const float np_ = naive_pred[blockBase + tid];

        // Dist arithmetic EXACTLY as round-1 (single sequential accumulator):
        // argmin is rounding-sensitive on near-ties; this order is validated.
        int bestk = 0;
        float bestd = INFINITY;
#pragma unroll 2
        for (int k = 0; k < Kc; ++k) {
            float dot = 0.f;
#pragma unroll
            for (int d = 0; d < DXc; ++d)
                dot = fmaf(xr[d], centers[k * DXc + d], dot);
            const float dist = fmaf(-2.0f, dot, sc2[k]);
            if (dist < bestd) { bestd = dist; bestk = k; }
        }

        // ---- Phase E: write s to LDS (padded), then SN dot with bestk row ----
#pragma unroll
        for (int i = 0; i < 4; ++i) {
            const int f = i * 256 + tid;                   // [0,1024): row=f>>2, col4=f&3
            sm.ss[(f >> 2) * 5 + (f & 3)] = st[i];
        }
        __syncthreads();

        float snacc = sbc[bestk];
#pragma unroll
        for (int i = 0; i < 4; ++i) {
            const float4 v = sm.ss[tid * 5 + i];
            snacc = fmaf(v.x, sWc[bestk][i * 4 + 0], snacc);
            snacc = fmaf(v.y, sWc[bestk][i * 4 + 1], snacc);
            snacc = fmaf(v.z, sWc[bestk][i * 4 + 2], snacc);
            snacc = fmaf(v.w, sWc[bestk][i * 4 + 3], snacc);
        }
        out[blockBase + tid] = snacc + x_tune * (np_ - snacc);

    } else {
        // ================= FALLBACK: partial block, per-thread =================
        const size_t b = blockBase + tid;
        if (b >= (size_t)n) return;

        float xr[DXc];
        const float4* x4 = reinterpret_cast<const float4*>(x + b * DXc);
#pragma unroll
        for (int i = 0; i < DXc / 4; ++i) {
            const float4 v = x4[i];
            xr[i * 4 + 0] = v.x; xr[i * 4 + 1] = v.y;
            xr[i * 4 + 2] = v.z; xr[i * 4 + 3] = v.w;
        }

        float hacc = 0.f;
        const float4* h4 = reinterpret_cast<const float4*>(hidden + b * Hc);
#pragma unroll 8
        for (int i = 0; i < Hc / 4; ++i) {
            const float4 v = h4[i];
            hacc = fmaf(v.x, W_tune[i * 4 + 0], hacc);
            hacc = fmaf(v.y, W_tune[i * 4 + 1], hacc);
            hacc = fmaf(v.z, W_tune[i * 4 + 2], hacc);
            hacc = fmaf(v.w, W_tune[i * 4 + 3], hacc);
        }
        const float z = hacc + b_tune[0];
        const float x_tune = 1.0f / (1.0f + __expf(-z));

        int bestk = 0;
        float bestd = INFINITY;
#pragma unroll 2
        for (int k = 0; k < Kc; ++k) {
            float dot = 0.f;
#pragma unroll
            for (int d = 0; d < DXc; ++d)
                dot = fmaf(xr[d], centers[k * DXc + d], dot);
            const float dist = fmaf(-2.0f, dot, sc2[k]);
            if (dist < bestd) { bestd = dist; bestk = k; }
        }

        float snacc = sbc[bestk];
        const float4* s4 = reinterpret_cast<const float4*>(s + b * DSc);
#pragma unroll
        for (int i = 0; i < DSc / 4; ++i) {
            const float4 v = s4[i];
            snacc = fmaf(v.x, sWc[bestk][i * 4 + 0], snacc);
            snacc = fmaf(v.y, sWc[bestk][i * 4 + 1], snacc);
            snacc = fmaf(v.z, sWc[bestk][i * 4 + 2], snacc);
            snacc = fmaf(v.w, sWc[bestk][i * 4 + 3], snacc);
        }
        const float np_ = naive_pred[b];
        out[b] = snacc + x_tune * (np_ - snacc);
    }
}

extern "C" void kernel_launch(void* const* d_in, const int* in_sizes, int n_in,
                              void* d_out, int out_size, void* d_ws, size_t ws_size,
                              hipStream_t stream) {
    const float* x          = (const float*)d_in[0];
    const float* s          = (const float*)d_in[1];
    const float* hidden     = (const float*)d_in[2];
    const float* naive_pred = (const float*)d_in[3];
    const float* centers    = (const float*)d_in[4];
    const float* W_tune     = (const float*)d_in[5];
    const float* b_tune     = (const float*)d_in[6];
    const float* W_sn       = (const float*)d_in[7];
    const float* b_sn       = (const float*)d_in[8];
    const float* rsw        = (const float*)d_in[9];
    float* out = (float*)d_out;

    const int n = in_sizes[3];  // B
    const int blocks = (n + 255) / 256;
    snclust_fused<<<blocks, 256, 0, stream>>>(x, s, hidden, naive_pred, centers,
                                              W_tune, b_tune, W_sn, b_sn, rsw,
                                              out, n);
}